// Round 1
// baseline (352.743 us; speedup 1.0000x reference)
//
#include <hip/hip_runtime.h>
#include <hip/hip_bf16.h>
#include <cstdint>

// ---------------------------------------------------------------------------
// TempoSpikeSelfAttention on MI355X (gfx950), bf16-MFMA pipeline.
//   dims: T=4 B=4 N=1024 D=768 H=12 Dh=64 -> M = T*B*N = 16384 rows
// Pipeline:
//   1. cast x, Wq|Wk|Wv (concat), Wo to bf16
//   2. QKV GEMM (m97 structure): QKV[16384, 2304] bf16, bias fused
//   3. transpose V -> Vt[(tb*12+h)*64 + d][1024]  (per-head d-major)
//   4. attention: per (tb,h,qtile64): S=QK^T (mfma 16x16x32), relu,
//      accumulate numerator P@V and denominator Sum(relu), normalize at end
//      -> CTX[16384, 768] bf16 (heads merged)
//   5. O GEMM: out = CTX @ Wo^T + bo  -> fp32 d_out
// ---------------------------------------------------------------------------

typedef __attribute__((ext_vector_type(8))) short short8;   // 8 bf16 = 4 VGPR
typedef __attribute__((ext_vector_type(4))) float float4v;  // mfma acc

__device__ __forceinline__ unsigned short f2bf(float f) {
  unsigned int u = __float_as_uint(f);
  u = (u + 0x7fffu + ((u >> 16) & 1u)) >> 16;   // RNE
  return (unsigned short)u;
}

// async global->LDS, 16B per lane; LDS dest = wave-uniform base + lane*16
__device__ __forceinline__ void gld_lds16(const void* g, void* lds) {
  __builtin_amdgcn_global_load_lds(
      (__attribute__((address_space(1))) void*)(uintptr_t)g,
      (__attribute__((address_space(3))) void*)(uint32_t)(uintptr_t)lds,
      16, 0, 0);
}

// ---------------------------------------------------------------------------
__global__ __launch_bounds__(256) void cast4(const float* __restrict__ src,
                                             unsigned short* __restrict__ dst,
                                             int n4) {
  int i = blockIdx.x * 256 + threadIdx.x;
  if (i >= n4) return;
  float4 f = reinterpret_cast<const float4*>(src)[i];
  ushort4 o;
  o.x = f2bf(f.x); o.y = f2bf(f.y); o.z = f2bf(f.z); o.w = f2bf(f.w);
  reinterpret_cast<ushort4*>(dst)[i] = o;
}

// ---------------------------------------------------------------------------
// C[i,j] = sum_k A[i,k] * Bt[j,k] + bias[j].  K=768 fixed. 128x128 tile, BK=32.
// 4 waves in 2x2, each 64x64 (4x4 mfma 16x16x32 tiles).
template <bool OUT_BF16>
__global__ __launch_bounds__(256) void gemm_bt(
    const unsigned short* __restrict__ A,   // [M,768] bf16
    const unsigned short* __restrict__ Bt,  // [N,768] bf16
    unsigned short* __restrict__ Cb,        // bf16 out [M,N]
    float* __restrict__ Cf,                 // f32 out  [M,N]
    const float* __restrict__ b0, const float* __restrict__ b1,
    const float* __restrict__ b2, int N) {
  constexpr int K = 768;
  __shared__ unsigned short As[128 * 32];   // packed: row stride 32 el (64 B)
  __shared__ unsigned short Bs[128 * 32];

  const int tid = threadIdx.x;
  const int lane = tid & 63;
  const int w = tid >> 6;
  const int wrow = w >> 1, wcol = w & 1;
  const int l15 = lane & 15, quad = lane >> 4;
  const int i0 = blockIdx.y * 128, j0 = blockIdx.x * 128;

  const unsigned short* ga = A + (size_t)(i0 + 32 * w + (lane >> 2)) * K + (lane & 3) * 8;
  const unsigned short* gb = Bt + (size_t)(j0 + 32 * w + (lane >> 2)) * K + (lane & 3) * 8;

  float4v acc[4][4];
#pragma unroll
  for (int a = 0; a < 4; ++a)
#pragma unroll
    for (int b = 0; b < 4; ++b) acc[a][b] = float4v{0.f, 0.f, 0.f, 0.f};

#pragma unroll 1
  for (int kt = 0; kt < K / 32; ++kt) {
    const unsigned short* pa = ga + kt * 32;
    const unsigned short* pb = gb + kt * 32;
    gld_lds16(pa, &As[(32 * w) * 32]);
    gld_lds16(pa + 16 * K, &As[(32 * w + 16) * 32]);
    gld_lds16(pb, &Bs[(32 * w) * 32]);
    gld_lds16(pb + 16 * K, &Bs[(32 * w + 16) * 32]);
    __syncthreads();   // drains vmcnt before barrier -> LDS tiles ready

    short8 af[4], bfr[4];
#pragma unroll
    for (int a = 0; a < 4; ++a)
      af[a] = *(const short8*)&As[(wrow * 64 + a * 16 + l15) * 32 + quad * 8];
#pragma unroll
    for (int b = 0; b < 4; ++b)
      bfr[b] = *(const short8*)&Bs[(wcol * 64 + b * 16 + l15) * 32 + quad * 8];
#pragma unroll
    for (int a = 0; a < 4; ++a)
#pragma unroll
      for (int b = 0; b < 4; ++b)
        acc[a][b] = __builtin_amdgcn_mfma_f32_16x16x32_bf16(af[a], bfr[b], acc[a][b], 0, 0, 0);
    __syncthreads();   // all reads done before next stage overwrites
  }

  const int sel = j0 / 768;
  const float* bp = (sel == 0) ? b0 : ((sel == 1) ? b1 : b2);
#pragma unroll
  for (int a = 0; a < 4; ++a) {
    const int row0 = i0 + wrow * 64 + a * 16 + quad * 4;
#pragma unroll
    for (int b = 0; b < 4; ++b) {
      const int col = j0 + wcol * 64 + b * 16 + l15;
      const float bias = bp[col - sel * 768];
#pragma unroll
      for (int r = 0; r < 4; ++r) {
        const float v = acc[a][b][r] + bias;
        if (OUT_BF16)
          Cb[(size_t)(row0 + r) * N + col] = f2bf(v);
        else
          Cf[(size_t)(row0 + r) * N + col] = v;
      }
    }
  }
}

// ---------------------------------------------------------------------------
// Vt[(tb*12+h)*64 + d][n] = QKV[(tb*1024+n)*2304 + 1536 + h*64 + d]
__global__ __launch_bounds__(256) void transpose_v(
    const unsigned short* __restrict__ qkv, unsigned short* __restrict__ vt) {
  __shared__ unsigned short T[64 * 72];
  const int bz = blockIdx.x;        // 192*16
  const int nt = bz & 15;
  const int tbh = bz >> 4;
  const int tb = tbh / 12, h = tbh % 12;
  const int tid = threadIdx.x;
#pragma unroll
  for (int it = 0; it < 2; ++it) {
    int c = tid + it * 256;
    int row = c >> 3, d0 = (c & 7) * 8;
    const unsigned short* g =
        qkv + (size_t)(tb * 1024 + nt * 64 + row) * 2304 + 1536 + h * 64 + d0;
    *(uint4*)&T[row * 72 + d0] = *(const uint4*)g;
  }
  __syncthreads();
#pragma unroll
  for (int it = 0; it < 2; ++it) {
    int c = tid + it * 256;
    int d = c >> 3, n0 = (c & 7) * 8;
    unsigned short tmp[8];
#pragma unroll
    for (int i = 0; i < 8; ++i) tmp[i] = T[(n0 + i) * 72 + d];
    *(uint4*)&vt[((size_t)(tb * 12 + h) * 64 + d) * 1024 + nt * 64 + n0] =
        *(uint4*)tmp;
  }
}

// ---------------------------------------------------------------------------
// Attention: block = (qt in 16, tbh in 192), 256 thr = 4 waves x 16 q-rows.
__global__ __launch_bounds__(256) void attn(
    const unsigned short* __restrict__ qkv,  // [16384, 2304] bf16
    const unsigned short* __restrict__ vt,   // [(tbh)*64 + d][1024] bf16
    unsigned short* __restrict__ ctx) {      // [16384, 768] bf16
  __shared__ unsigned short Qs[64 * 72];
  __shared__ unsigned short Ks[64 * 72];
  __shared__ unsigned short Vs[64 * 72];   // rows = d, cols = m
  __shared__ unsigned short Ps[4 * 16 * 72];

  const int qt = blockIdx.x;
  const int tbh = blockIdx.y;
  const int tb = tbh / 12, h = tbh % 12;
  const int tid = threadIdx.x, lane = tid & 63, w = tid >> 6;
  const int l15 = lane & 15, quad = lane >> 4;

  // stage Q tile [64 rows][64 d] (padded stride 72)
#pragma unroll
  for (int it = 0; it < 2; ++it) {
    int c = tid + it * 256;
    int row = c >> 3, d0 = (c & 7) * 8;
    const unsigned short* g =
        qkv + (size_t)(tb * 1024 + qt * 64 + row) * 2304 + h * 64 + d0;
    *(uint4*)&Qs[row * 72 + d0] = *(const uint4*)g;
  }
  __syncthreads();
  short8 qf[2];   // A-frags, hoisted: lane holds Q[w*16 + l15][c*32 + quad*8 + j]
#pragma unroll
  for (int c = 0; c < 2; ++c)
    qf[c] = *(const short8*)&Qs[(w * 16 + l15) * 72 + c * 32 + quad * 8];

  float4v octx[4];
#pragma unroll
  for (int b = 0; b < 4; ++b) octx[b] = float4v{0.f, 0.f, 0.f, 0.f};
  float den[4] = {0.f, 0.f, 0.f, 0.f};
  unsigned short* Psw = &Ps[w * 16 * 72];

#pragma unroll 1
  for (int kv = 0; kv < 16; ++kv) {
    __syncthreads();   // previous iter's K/V reads complete
#pragma unroll
    for (int it = 0; it < 2; ++it) {
      int c = tid + it * 256;
      int row = c >> 3, d0 = (c & 7) * 8;
      *(uint4*)&Ks[row * 72 + d0] = *(const uint4*)(
          qkv + (size_t)(tb * 1024 + kv * 64 + row) * 2304 + 768 + h * 64 + d0);
      *(uint4*)&Vs[row * 72 + d0] = *(const uint4*)(
          vt + ((size_t)(tb * 12 + h) * 64 + row) * 1024 + kv * 64 + d0);
    }
    __syncthreads();

    // S = Q K^T (raw, unscaled)
    float4v sa[4];
#pragma unroll
    for (int s = 0; s < 4; ++s) sa[s] = float4v{0.f, 0.f, 0.f, 0.f};
#pragma unroll
    for (int s = 0; s < 4; ++s)
#pragma unroll
      for (int c = 0; c < 2; ++c) {
        short8 kf = *(const short8*)&Ks[(s * 16 + l15) * 72 + c * 32 + quad * 8];
        sa[s] = __builtin_amdgcn_mfma_f32_16x16x32_bf16(qf[c], kf, sa[s], 0, 0, 0);
      }

    // relu, denominator accumulate, P -> LDS (C-layout -> A-layout transform)
#pragma unroll
    for (int s = 0; s < 4; ++s)
#pragma unroll
      for (int r = 0; r < 4; ++r) {
        float v = sa[s][r];
        v = v > 0.f ? v : 0.f;
        den[r] += v;
        Psw[(quad * 4 + r) * 72 + s * 16 + l15] = f2bf(v);
      }
    // same-wave LDS RAW: DS ops from one wave execute in order

    // octx += P @ V
#pragma unroll
    for (int c = 0; c < 2; ++c) {
      short8 pf = *(const short8*)&Psw[l15 * 72 + c * 32 + quad * 8];
#pragma unroll
      for (int b = 0; b < 4; ++b) {
        short8 vf = *(const short8*)&Vs[(b * 16 + l15) * 72 + c * 32 + quad * 8];
        octx[b] = __builtin_amdgcn_mfma_f32_16x16x32_bf16(pf, vf, octx[b], 0, 0, 0);
      }
    }
  }

  // denominator: sum across the 16 lanes of each quad (covers all 64 cols/tile)
#pragma unroll
  for (int r = 0; r < 4; ++r) {
    float d = den[r];
    d += __shfl_xor(d, 1);
    d += __shfl_xor(d, 2);
    d += __shfl_xor(d, 4);
    d += __shfl_xor(d, 8);
    den[r] = 1.f / (d + 8e-6f);   // folded: relu(s)/(sum relu(s) + 8*EPS*... ) == ref
  }

#pragma unroll
  for (int b = 0; b < 4; ++b)
#pragma unroll
    for (int r = 0; r < 4; ++r) {
      const int row = tb * 1024 + qt * 64 + w * 16 + quad * 4 + r;
      const int col = h * 64 + b * 16 + l15;
      ctx[(size_t)row * 768 + col] = f2bf(octx[b][r] * den[r]);
    }
}

// ---------------------------------------------------------------------------
extern "C" void kernel_launch(void* const* d_in, const int* in_sizes, int n_in,
                              void* d_out, int out_size, void* d_ws, size_t ws_size,
                              hipStream_t stream) {
  const float* x  = (const float*)d_in[0];
  const float* Wq = (const float*)d_in[1];
  const float* bq = (const float*)d_in[2];
  const float* Wk = (const float*)d_in[3];
  const float* bk = (const float*)d_in[4];
  const float* Wv = (const float*)d_in[5];
  const float* bv = (const float*)d_in[6];
  const float* Wo = (const float*)d_in[7];
  const float* bo = (const float*)d_in[8];
  float* out = (float*)d_out;

  char* ws = (char*)d_ws;
  // workspace layout (bytes); CTX aliases XBF (XBF dead after QKV GEMM)
  unsigned short* XBF  = (unsigned short*)(ws);                  // 25165824 B
  unsigned short* CTX  = (unsigned short*)(ws);                  // alias
  unsigned short* WQKV = (unsigned short*)(ws + 25165824);       //  3538944 B
  unsigned short* WOb  = (unsigned short*)(ws + 28704768);       //  1179648 B
  unsigned short* QKV  = (unsigned short*)(ws + 29884416);       // 75497472 B
  unsigned short* VT   = (unsigned short*)(ws + 105381888);      // 25165824 B
  // total: 130547712 B

  cast4<<<12288, 256, 0, stream>>>(x, XBF, 3145728);
  cast4<<<576, 256, 0, stream>>>(Wq, WQKV, 147456);
  cast4<<<576, 256, 0, stream>>>(Wk, WQKV + 589824, 147456);
  cast4<<<576, 256, 0, stream>>>(Wv, WQKV + 1179648, 147456);
  cast4<<<576, 256, 0, stream>>>(Wo, WOb, 147456);

  gemm_bt<true><<<dim3(18, 128), 256, 0, stream>>>(XBF, WQKV, QKV, nullptr,
                                                   bq, bk, bv, 2304);
  transpose_v<<<3072, 256, 0, stream>>>(QKV, VT);
  attn<<<dim3(16, 192), 256, 0, stream>>>(QKV, VT, CTX);
  gemm_bt<false><<<dim3(6, 128), 256, 0, stream>>>(CTX, WOb, nullptr, out,
                                                   bo, bo, bo, 768);
}

// Round 2
// 342.905 us; speedup vs baseline: 1.0287x; 1.0287x over previous
//
#include <hip/hip_runtime.h>
#include <hip/hip_bf16.h>
#include <cstdint>

// ---------------------------------------------------------------------------
// TempoSpikeSelfAttention on MI355X (gfx950), bf16-MFMA pipeline.
//   dims: T=4 B=4 N=1024 D=768 H=12 Dh=64 -> M = T*B*N = 16384 rows
// Pipeline:
//   1. cast x, Wq|Wk|Wv (concat), Wo to bf16
//   2. QKV GEMM (m97 structure): QKV[16384, 2304] bf16, bias fused
//   3. transpose V -> Vt[(tb*12+h)*64 + d][1024]  (per-head d-major)
//   4. attn32: per (tb,h,qtile128): S^T = K Q^T via mfma 32x32x16 (C layout
//      gives 4 contiguous kv per reg-quad -> b64-packed P writes in A-layout),
//      relu + fp32 denominator, octx += P V, normalize at end.
//   5. O GEMM: out = CTX @ Wo^T + bo  -> fp32 d_out
// ---------------------------------------------------------------------------

typedef __attribute__((ext_vector_type(8))) short short8;     // 8 bf16 = 4 VGPR
typedef __attribute__((ext_vector_type(4))) float float4v;    // 16x16 acc
typedef __attribute__((ext_vector_type(16))) float float16v;  // 32x32 acc

__device__ __forceinline__ unsigned short f2bf(float f) {
  unsigned int u = __float_as_uint(f);
  u = (u + 0x7fffu + ((u >> 16) & 1u)) >> 16;   // RNE
  return (unsigned short)u;
}

// pack two f32 -> two bf16 (round-half-away) in one v_perm_b32
__device__ __forceinline__ unsigned int pkbf(float a, float b) {
  unsigned int ua = __float_as_uint(a) + 0x8000u;
  unsigned int ub = __float_as_uint(b) + 0x8000u;
  return __builtin_amdgcn_perm(ub, ua, 0x07060302u);  // [bf(a) lo16 | bf(b) hi16]
}

// async global->LDS, 16B per lane; LDS dest = wave-uniform base + lane*16
__device__ __forceinline__ void gld_lds16(const void* g, void* lds) {
  __builtin_amdgcn_global_load_lds(
      (__attribute__((address_space(1))) void*)(uintptr_t)g,
      (__attribute__((address_space(3))) void*)(uint32_t)(uintptr_t)lds,
      16, 0, 0);
}

// ---------------------------------------------------------------------------
__global__ __launch_bounds__(256) void cast4(const float* __restrict__ src,
                                             unsigned short* __restrict__ dst,
                                             int n4) {
  int i = blockIdx.x * 256 + threadIdx.x;
  if (i >= n4) return;
  float4 f = reinterpret_cast<const float4*>(src)[i];
  ushort4 o;
  o.x = f2bf(f.x); o.y = f2bf(f.y); o.z = f2bf(f.z); o.w = f2bf(f.w);
  reinterpret_cast<ushort4*>(dst)[i] = o;
}

// ---------------------------------------------------------------------------
// C[i,j] = sum_k A[i,k] * Bt[j,k] + bias[j].  K=768 fixed. 128x128 tile, BK=32.
// 4 waves in 2x2, each 64x64 (4x4 mfma 16x16x32 tiles).
template <bool OUT_BF16>
__global__ __launch_bounds__(256) void gemm_bt(
    const unsigned short* __restrict__ A,   // [M,768] bf16
    const unsigned short* __restrict__ Bt,  // [N,768] bf16
    unsigned short* __restrict__ Cb,        // bf16 out [M,N]
    float* __restrict__ Cf,                 // f32 out  [M,N]
    const float* __restrict__ b0, const float* __restrict__ b1,
    const float* __restrict__ b2, int N) {
  constexpr int K = 768;
  __shared__ unsigned short As[128 * 32];   // packed: row stride 32 el (64 B)
  __shared__ unsigned short Bs[128 * 32];

  const int tid = threadIdx.x;
  const int lane = tid & 63;
  const int w = tid >> 6;
  const int wrow = w >> 1, wcol = w & 1;
  const int l15 = lane & 15, quad = lane >> 4;
  const int i0 = blockIdx.y * 128, j0 = blockIdx.x * 128;

  const unsigned short* ga = A + (size_t)(i0 + 32 * w + (lane >> 2)) * K + (lane & 3) * 8;
  const unsigned short* gb = Bt + (size_t)(j0 + 32 * w + (lane >> 2)) * K + (lane & 3) * 8;

  float4v acc[4][4];
#pragma unroll
  for (int a = 0; a < 4; ++a)
#pragma unroll
    for (int b = 0; b < 4; ++b) acc[a][b] = float4v{0.f, 0.f, 0.f, 0.f};

#pragma unroll 1
  for (int kt = 0; kt < K / 32; ++kt) {
    const unsigned short* pa = ga + kt * 32;
    const unsigned short* pb = gb + kt * 32;
    gld_lds16(pa, &As[(32 * w) * 32]);
    gld_lds16(pa + 16 * K, &As[(32 * w + 16) * 32]);
    gld_lds16(pb, &Bs[(32 * w) * 32]);
    gld_lds16(pb + 16 * K, &Bs[(32 * w + 16) * 32]);
    __syncthreads();   // drains vmcnt before barrier -> LDS tiles ready

    short8 af[4], bfr[4];
#pragma unroll
    for (int a = 0; a < 4; ++a)
      af[a] = *(const short8*)&As[(wrow * 64 + a * 16 + l15) * 32 + quad * 8];
#pragma unroll
    for (int b = 0; b < 4; ++b)
      bfr[b] = *(const short8*)&Bs[(wcol * 64 + b * 16 + l15) * 32 + quad * 8];
#pragma unroll
    for (int a = 0; a < 4; ++a)
#pragma unroll
      for (int b = 0; b < 4; ++b)
        acc[a][b] = __builtin_amdgcn_mfma_f32_16x16x32_bf16(af[a], bfr[b], acc[a][b], 0, 0, 0);
    __syncthreads();   // all reads done before next stage overwrites
  }

  const int sel = j0 / 768;
  const float* bp = (sel == 0) ? b0 : ((sel == 1) ? b1 : b2);
#pragma unroll
  for (int a = 0; a < 4; ++a) {
    const int row0 = i0 + wrow * 64 + a * 16 + quad * 4;
#pragma unroll
    for (int b = 0; b < 4; ++b) {
      const int col = j0 + wcol * 64 + b * 16 + l15;
      const float bias = bp[col - sel * 768];
#pragma unroll
      for (int r = 0; r < 4; ++r) {
        const float v = acc[a][b][r] + bias;
        if (OUT_BF16)
          Cb[(size_t)(row0 + r) * N + col] = f2bf(v);
        else
          Cf[(size_t)(row0 + r) * N + col] = v;
      }
    }
  }
}

// ---------------------------------------------------------------------------
// Vt[(tb*12+h)*64 + d][n] = QKV[(tb*1024+n)*2304 + 1536 + h*64 + d]
__global__ __launch_bounds__(256) void transpose_v(
    const unsigned short* __restrict__ qkv, unsigned short* __restrict__ vt) {
  __shared__ unsigned short T[64 * 72];
  const int bz = blockIdx.x;        // 192*16
  const int nt = bz & 15;
  const int tbh = bz >> 4;
  const int tb = tbh / 12, h = tbh % 12;
  const int tid = threadIdx.x;
#pragma unroll
  for (int it = 0; it < 2; ++it) {
    int c = tid + it * 256;
    int row = c >> 3, d0 = (c & 7) * 8;
    const unsigned short* g =
        qkv + (size_t)(tb * 1024 + nt * 64 + row) * 2304 + 1536 + h * 64 + d0;
    *(uint4*)&T[row * 72 + d0] = *(const uint4*)g;
  }
  __syncthreads();
#pragma unroll
  for (int it = 0; it < 2; ++it) {
    int c = tid + it * 256;
    int d = c >> 3, n0 = (c & 7) * 8;
    unsigned short tmp[8];
#pragma unroll
    for (int i = 0; i < 8; ++i) tmp[i] = T[(n0 + i) * 72 + d];
    *(uint4*)&vt[((size_t)(tb * 12 + h) * 64 + d) * 1024 + nt * 64 + n0] =
        *(uint4*)tmp;
  }
}

// ---------------------------------------------------------------------------
// Attention, 32x32x16 MFMA. Block = (qt in 8, tbh in 192), 256 thr = 4 waves.
// Wave w owns q rows [w*32, w*32+32). Per kv-tile (64 keys):
//   S^T = K.Q^T  (A=K rows, B=Q rows; C: row=kv, col=q=lane&31)
//   relu -> den (scalar/lane) ; P packed to LDS rows [q][kv] (A-layout)
//   octx += P.V (A=P rows, B=Vt rows; C: row=q, col=d=lane&31)
__global__ __launch_bounds__(256) void attn32(
    const unsigned short* __restrict__ qkv,  // [16384, 2304] bf16
    const unsigned short* __restrict__ vt,   // [(tbh)*64 + d][1024] bf16
    unsigned short* __restrict__ ctx) {      // [16384, 768] bf16
  __shared__ unsigned short QP[128 * 72];    // Q staging, then per-wave P
  __shared__ unsigned short Ks[64 * 72];
  __shared__ unsigned short Vs[64 * 72];     // rows = d, cols = kv

  const int qt = blockIdx.x;                 // 8 tiles of 128 q-rows
  const int tbh = blockIdx.y;
  const int tb = tbh / 12, h = tbh % 12;
  const int tid = threadIdx.x, lane = tid & 63, w = tid >> 6;
  const int l31 = lane & 31, hl = lane >> 5;

  // stage Q tile: 128 rows x 64 d (padded stride 72)
#pragma unroll
  for (int it = 0; it < 4; ++it) {
    int c = it * 256 + tid;
    int row = c >> 3, col = (c & 7) * 8;
    *(uint4*)&QP[row * 72 + col] = *(const uint4*)(
        qkv + (size_t)(tb * 1024 + qt * 128 + row) * 2304 + h * 64 + col);
  }
  __syncthreads();

  // hoist Q frags: lane holds Q[q = w*32+l31][d = kc*16 + hl*8 + j]
  short8 qf[4];
#pragma unroll
  for (int kc = 0; kc < 4; ++kc)
    qf[kc] = *(const short8*)&QP[(w * 32 + l31) * 72 + kc * 16 + hl * 8];
  // wave-private P region = exactly the rows this wave just read
  unsigned short* PW = &QP[(w * 32) * 72];

  float16v octx[2];
#pragma unroll
  for (int i = 0; i < 16; ++i) { octx[0][i] = 0.f; octx[1][i] = 0.f; }
  float den = 0.f;

#pragma unroll 1
  for (int kv = 0; kv < 16; ++kv) {
    __syncthreads();   // previous iter's Ks/Vs reads complete
#pragma unroll
    for (int it = 0; it < 2; ++it) {
      int c = it * 256 + tid;
      int row = c >> 3, col = (c & 7) * 8;
      *(uint4*)&Ks[row * 72 + col] = *(const uint4*)(
          qkv + (size_t)(tb * 1024 + kv * 64 + row) * 2304 + 768 + h * 64 + col);
      *(uint4*)&Vs[row * 72 + col] = *(const uint4*)(
          vt + ((size_t)(tb * 12 + h) * 64 + row) * 1024 + kv * 64 + col);
    }
    __syncthreads();

    // S^T tiles (kv-local 32-row tiles mt), then relu+pack straight to P
#pragma unroll
    for (int mt = 0; mt < 2; ++mt) {
      float16v st;
#pragma unroll
      for (int i = 0; i < 16; ++i) st[i] = 0.f;
#pragma unroll
      for (int kc = 0; kc < 4; ++kc) {
        short8 af = *(const short8*)&Ks[(mt * 32 + l31) * 72 + kc * 16 + hl * 8];
        st = __builtin_amdgcn_mfma_f32_32x32x16_bf16(af, qf[kc], st, 0, 0, 0);
      }
      // C layout: col=q=l31, row=kv_local = (reg&3) + 8*(reg>>2) + 4*hl
      // reg group g: 4 contiguous kv at mt*32 + 8g + 4hl -> one b64 write
#pragma unroll
      for (int g = 0; g < 4; ++g) {
        float v0 = st[4 * g + 0]; v0 = v0 > 0.f ? v0 : 0.f;
        float v1 = st[4 * g + 1]; v1 = v1 > 0.f ? v1 : 0.f;
        float v2 = st[4 * g + 2]; v2 = v2 > 0.f ? v2 : 0.f;
        float v3 = st[4 * g + 3]; v3 = v3 > 0.f ? v3 : 0.f;
        den += (v0 + v1) + (v2 + v3);
        uint2 u;
        u.x = pkbf(v0, v1);
        u.y = pkbf(v2, v3);
        *(uint2*)&PW[l31 * 72 + mt * 32 + g * 8 + hl * 4] = u;
      }
    }

    // PV: A-frags from P (same-wave LDS RAW, DS ops in order)
    short8 pa[4];
#pragma unroll
    for (int kc = 0; kc < 4; ++kc)
      pa[kc] = *(const short8*)&PW[l31 * 72 + kc * 16 + hl * 8];
#pragma unroll
    for (int dt = 0; dt < 2; ++dt)
#pragma unroll
      for (int kc = 0; kc < 4; ++kc) {
        short8 vb = *(const short8*)&Vs[(dt * 32 + l31) * 72 + kc * 16 + hl * 8];
        octx[dt] = __builtin_amdgcn_mfma_f32_32x32x16_bf16(pa[kc], vb, octx[dt], 0, 0, 0);
      }
  }

  // den currently: sum over this half-wave's kv rows for q=l31
  den += __shfl_xor(den, 32);
  __syncthreads();                 // all waves done reading Ks
  float* dsc = (float*)Ks;         // reuse as per-wave scale scratch
  if (hl == 0) dsc[w * 32 + l31] = 1.f / (den + 8e-6f);  // folded 1/sqrt(64)
  __syncthreads();

#pragma unroll
  for (int dt = 0; dt < 2; ++dt)
#pragma unroll
    for (int reg = 0; reg < 16; ++reg) {
      const int qrow = (reg & 3) + 8 * (reg >> 2) + 4 * hl;
      const float sc = dsc[w * 32 + qrow];
      const int grow = tb * 1024 + qt * 128 + w * 32 + qrow;
      ctx[(size_t)grow * 768 + h * 64 + dt * 32 + l31] =
          f2bf(octx[dt][reg] * sc);
    }
}

// ---------------------------------------------------------------------------
extern "C" void kernel_launch(void* const* d_in, const int* in_sizes, int n_in,
                              void* d_out, int out_size, void* d_ws, size_t ws_size,
                              hipStream_t stream) {
  const float* x  = (const float*)d_in[0];
  const float* Wq = (const float*)d_in[1];
  const float* bq = (const float*)d_in[2];
  const float* Wk = (const float*)d_in[3];
  const float* bk = (const float*)d_in[4];
  const float* Wv = (const float*)d_in[5];
  const float* bv = (const float*)d_in[6];
  const float* Wo = (const float*)d_in[7];
  const float* bo = (const float*)d_in[8];
  float* out = (float*)d_out;

  char* ws = (char*)d_ws;
  // workspace layout (bytes); CTX aliases XBF (XBF dead after QKV GEMM)
  unsigned short* XBF  = (unsigned short*)(ws);                  // 25165824 B
  unsigned short* CTX  = (unsigned short*)(ws);                  // alias
  unsigned short* WQKV = (unsigned short*)(ws + 25165824);       //  3538944 B
  unsigned short* WOb  = (unsigned short*)(ws + 28704768);       //  1179648 B
  unsigned short* QKV  = (unsigned short*)(ws + 29884416);       // 75497472 B
  unsigned short* VT   = (unsigned short*)(ws + 105381888);      // 25165824 B
  // total: 130547712 B

  cast4<<<12288, 256, 0, stream>>>(x, XBF, 3145728);
  cast4<<<576, 256, 0, stream>>>(Wq, WQKV, 147456);
  cast4<<<576, 256, 0, stream>>>(Wk, WQKV + 589824, 147456);
  cast4<<<576, 256, 0, stream>>>(Wv, WQKV + 1179648, 147456);
  cast4<<<576, 256, 0, stream>>>(Wo, WOb, 147456);

  gemm_bt<true><<<dim3(18, 128), 256, 0, stream>>>(XBF, WQKV, QKV, nullptr,
                                                   bq, bk, bv, 2304);
  transpose_v<<<3072, 256, 0, stream>>>(QKV, VT);
  attn32<<<dim3(8, 192), 256, 0, stream>>>(QKV, VT, CTX);
  gemm_bt<false><<<dim3(6, 128), 256, 0, stream>>>(CTX, WOb, nullptr, out,
                                                   bo, bo, bo, 768);
}